// Round 5
// baseline (161.036 us; speedup 1.0000x reference)
//
#include <hip/hip_runtime.h>
#include <hip/hip_bf16.h>

#define BATCH 16
#define CI 64
#define CO 64
#define H 128
#define W 128
#define HO 126
#define WO 126

#define XC 68                 // staged cols per block (64 out + 2 halo + 2 pad)
#define SLAB (XC * 8 * 8)     // shorts per row-slab = 4352 (8704 B)

typedef short bfrag __attribute__((ext_vector_type(8)));   // 8 bf16 = 4 VGPRs
typedef float ffrag __attribute__((ext_vector_type(4)));   // 4 fp32 acc

static __device__ __forceinline__ unsigned short f2bf(float f) {
    unsigned u = __float_as_uint(f);
    u += 0x7fffu + ((u >> 16) & 1u);      // RNE
    return (unsigned short)(u >> 16);
}

// prepass: w[b][co][ci][dy][dx] fp32 -> w_t[b][s][co][ci] bf16  (s = dy*3+dx)
__global__ void wt_prepass(const float* __restrict__ w, unsigned short* __restrict__ w_t) {
    int i = blockIdx.x * 256 + threadIdx.x;          // 589824 total
    int ci = i & 63;
    int co = (i >> 6) & 63;
    int bs = i >> 12;
    int b = bs / 9, s = bs - b * 9;
    w_t[i] = f2bf(w[(((b * 64 + co) * 64 + ci) * 9) + s]);
}

// Fused dynamic conv: block = (2 out rows) x (64 out cols) x (all 64 co).
// LDS 34.8 KB -> 4 blocks/CU for latency hiding.  Chunk (col,o) holds
// ci o*8..o*8+7 at slab index col*8 + (o ^ (col&7)) -> B-frag ds_read_b128
// conflict-free (0 conflicts measured R3/R4); staging writes hit all 32 banks.
__launch_bounds__(256, 4)
__global__ void dynconv_fused(const float* __restrict__ x,
                              const unsigned short* __restrict__ w_t,
                              const float* __restrict__ bias,
                              float* __restrict__ out) {
    __shared__ __align__(16) unsigned short xs[4 * SLAB];   // 34,816 B

    const int tid  = threadIdx.x;
    const int rg   = blockIdx.x;       // 0..62: 2 output rows each
    const int ct   = blockIdx.y;       // 0..1:  64-col tile
    const int b    = blockIdx.z;
    const int y0   = rg * 2;
    const int x0   = ct * 64;
    const int wave = tid >> 6;
    const int lane = tid & 63;
    const int l16  = lane & 15;
    const int lq   = lane >> 4;
    const int wm   = wave & 1;         // co half
    const int wn   = wave >> 1;        // output row within tile

    // ---- fused stage: 2176 chunks = 4 rows x 8 octets x 68 cols (col fastest)
    {
        const float* xb = x + (size_t)b * CI * H * W;
        #pragma unroll
        for (int it = 0; it < 9; ++it) {
            int i = it * 256 + tid;
            if (i < 4 * 8 * XC) {
                int row = i / (8 * XC);
                int rem = i - row * (8 * XC);
                int o   = rem / XC;
                int col = rem - o * XC;
                int gx  = x0 + col; if (gx > 127) gx = 127;   // junk -> discarded cols
                const float* p = xb + ((size_t)(o * 8) * H + (y0 + row)) * W + gx;
                unsigned int u[4];
                #pragma unroll
                for (int e = 0; e < 4; ++e) {
                    float f0 = p[(size_t)(2 * e) * (H * W)];
                    float f1 = p[(size_t)(2 * e + 1) * (H * W)];
                    __hip_bfloat162 h2 = __float22bfloat162_rn(make_float2(f0, f1));
                    u[e] = *(unsigned int*)&h2;               // low = even ci ✓
                }
                *(uint4*)&xs[row * SLAB + (col * 8 + (o ^ (col & 7))) * 8] = *(const uint4*)u;
            }
        }
    }

    // ---- A-frag prefetch for shift 0 (w_t L2-resident)
    const bfrag* wtb = (const bfrag*)w_t + (size_t)(b * 9) * 512;   // 512 chunks/shift
    const int co_b = wm * 32 + l16;
    bfrag acur[4], anxt[4];
    #pragma unroll
    for (int ks = 0; ks < 2; ++ks)
        #pragma unroll
        for (int mt = 0; mt < 2; ++mt)
            acur[ks * 2 + mt] = wtb[(co_b + mt * 16) * 8 + ks * 4 + lq];

    ffrag acc[2][4];
    #pragma unroll
    for (int mt = 0; mt < 2; ++mt)
        #pragma unroll
        for (int nt = 0; nt < 4; ++nt)
            acc[mt][nt] = (ffrag){0.f, 0.f, 0.f, 0.f};

    __syncthreads();   // the only barrier: staging complete

    for (int s = 0; s < 9; ++s) {
        if (s < 8) {
            const bfrag* wn2 = wtb + (s + 1) * 512;
            #pragma unroll
            for (int ks = 0; ks < 2; ++ks)
                #pragma unroll
                for (int mt = 0; mt < 2; ++mt)
                    anxt[ks * 2 + mt] = wn2[(co_b + mt * 16) * 8 + ks * 4 + lq];
        }
        const int dy = s / 3, dx = s - dy * 3;
        const int xr = wn + dy;            // staged row-slab 0..3
        #pragma unroll
        for (int ks = 0; ks < 2; ++ks) {
            const int o = ks * 4 + lq;     // ci octet for this lane's k-slice
            #pragma unroll
            for (int nt = 0; nt < 4; ++nt) {
                int colx = nt * 16 + l16 + dx;          // <= 65, in slab
                const bfrag bf = *(const bfrag*)&xs[xr * SLAB + (colx * 8 + (o ^ (colx & 7))) * 8];
                acc[0][nt] = __builtin_amdgcn_mfma_f32_16x16x32_bf16(acur[ks * 2 + 0], bf, acc[0][nt], 0, 0, 0);
                acc[1][nt] = __builtin_amdgcn_mfma_f32_16x16x32_bf16(acur[ks * 2 + 1], bf, acc[1][nt], 0, 0, 0);
            }
        }
        #pragma unroll
        for (int j = 0; j < 4; ++j) acur[j] = anxt[j];
    }

    // ---- epilogue: bias + store (C/D: col = lane&15, row = quad*4 + reg)
    const int oy = y0 + wn;                // <= 125
    #pragma unroll
    for (int mt = 0; mt < 2; ++mt) {
        #pragma unroll
        for (int r = 0; r < 4; ++r) {
            int co = wm * 32 + mt * 16 + lq * 4 + r;
            float bv = bias[b * 64 + co];
            float* op = out + ((size_t)(b * 64 + co) * HO + oy) * WO;
            #pragma unroll
            for (int nt = 0; nt < 4; ++nt) {
                int ox = x0 + nt * 16 + l16;
                if (ox < WO) op[ox] = acc[mt][nt][r] + bv;
            }
        }
    }
}

extern "C" void kernel_launch(void* const* d_in, const int* in_sizes, int n_in,
                              void* d_out, int out_size, void* d_ws, size_t ws_size,
                              hipStream_t stream) {
    const float* x    = (const float*)d_in[0];
    const float* w    = (const float*)d_in[1];
    const float* bias = (const float*)d_in[2];
    float* out        = (float*)d_out;

    unsigned short* w_t = (unsigned short*)d_ws;   // 1,179,648 B

    wt_prepass<<<dim3(589824 / 256), dim3(256), 0, stream>>>(w, w_t);
    dynconv_fused<<<dim3(63, 2, BATCH), dim3(256), 0, stream>>>(x, w_t, bias, out);
}